// Round 3
// baseline (475.321 us; speedup 1.0000x reference)
//
#include <hip/hip_runtime.h>

// SRM neuron: per-row 50-tap 'same' conv -> threshold -> refractory scan.
// B=4096 rows, T=16384. One wave per row.
// R3: ownership granularity = 4 consecutive timesteps/lane so that every
//     global load/store instruction is fully contiguous (lane i <-> byte 16i).
//     R2's 32B-strided float4 pairs caused 4.8x read / 1.66x write HBM
//     amplification (partial 64B sectors).

#define TLEN  16384
#define NROWS 4096
#define GRP   256     // elements per group (64 lanes x 4)
#define NGRP  64      // TLEN / GRP
#define KLEN  50
#define WPB   4       // waves (rows) per 256-thread block

__device__ __forceinline__ float uniformf(float x) {
    return __int_as_float(__builtin_amdgcn_readfirstlane(__float_as_int(x)));
}

// compose: r[s] = then[first[s]]  (apply `first`, then `then`)
__device__ __forceinline__ int map_compose(int first, int then) {
    int r = 0;
#pragma unroll
    for (int s = 0; s < 4; ++s) {
        int a = (first >> (2 * s)) & 3;
        int b = (then >> (2 * a)) & 3;
        r |= b << (2 * s);
    }
    return r;
}

__global__ __launch_bounds__(256, 4)
void srm_kernel(const float* __restrict__ I,
                const float* __restrict__ p_tau_m,
                const float* __restrict__ p_tau_s,
                const float* __restrict__ p_v_th,
                const float* __restrict__ p_v_reset,
                float* __restrict__ out)
{
    const int lane = threadIdx.x & 63;
    const int wid  = threadIdx.x >> 6;
    const int row  = blockIdx.x * WPB + wid;

    const float tau_m   = p_tau_m[0];
    const float tau_s   = p_tau_s[0];
    const float v_th    = p_v_th[0];
    const float v_reset = p_v_reset[0];

    // Taps pinned wave-uniform (SGPR file) -- same arithmetic as R1/R2
    // which validated bit-exact.
    float ku[KLEN];
    float ksum = 0.0f;
#pragma unroll
    for (int t = 0; t < KLEN; ++t) {
        float ft = (float)t;
        float v = expf(-ft / tau_m) - expf(-ft / tau_s);
        ksum += v;
        ku[t] = uniformf(v);
    }
    const float kden = uniformf(ksum + 1e-10f);
    float kt[KLEN];
#pragma unroll
    for (int t = 0; t < KLEN; ++t) kt[t] = uniformf(ku[t] / kden);

    const float* Irow = I + (size_t)row * TLEN;
    float* Orow = out + (size_t)row * TLEN;

    // Rotating per-group register sets (4 floats/lane per 256-elem group).
    float Pv[4], Cv[4], Nv[4];
#pragma unroll
    for (int j = 0; j < 4; ++j) Pv[j] = 0.0f;   // x[t<0] = 0

    {
        float4 a = *(const float4*)(Irow + 0 * GRP + 4 * lane);
        Cv[0] = a.x; Cv[1] = a.y; Cv[2] = a.z; Cv[3] = a.w;
        float4 c = *(const float4*)(Irow + 1 * GRP + 4 * lane);
        Nv[0] = c.x; Nv[1] = c.y; Nv[2] = c.z; Nv[3] = c.w;
    }

    // bpermute byte-addresses for lane shifts q = -7..6
    const int addr_m7 = ((lane - 7) & 63) << 2;
    const int addr_m6 = ((lane - 6) & 63) << 2;
    const int addr_m5 = ((lane - 5) & 63) << 2;
    const int addr_m4 = ((lane - 4) & 63) << 2;
    const int addr_m3 = ((lane - 3) & 63) << 2;
    const int addr_m2 = ((lane - 2) & 63) << 2;
    const int addr_m1 = ((lane - 1) & 63) << 2;
    const int addr_p1 = ((lane + 1) & 63) << 2;
    const int addr_p2 = ((lane + 2) & 63) << 2;
    const int addr_p3 = ((lane + 3) & 63) << 2;
    const int addr_p4 = ((lane + 4) & 63) << 2;
    const int addr_p5 = ((lane + 5) & 63) << 2;
    const int addr_p6 = ((lane + 6) & 63) << 2;

    int r0 = 0;  // wave-uniform refractory state entering this group

    for (int g = 0; g < NGRP; ++g) {
        // ---- prefetch group g+2 (zeros past the end), 1 contiguous float4 ----
        float Lv[4];
        if (g + 2 < NGRP) {
            float4 a = *(const float4*)(Irow + (size_t)(g + 2) * GRP + 4 * lane);
            Lv[0] = a.x; Lv[1] = a.y; Lv[2] = a.z; Lv[3] = a.w;
        } else {
            Lv[0] = Lv[1] = Lv[2] = Lv[3] = 0.0f;
        }

        // ---- convolution: out[4l+k] = sum_j kt[j] * x[g*256 + 4l + k + 24 - j] ----
        float acc[4];
        acc[0] = acc[1] = acc[2] = acc[3] = 0.0f;

#pragma unroll
        for (int o = -25; o <= 27; ++o) {      // window offset rel. to 4l
            const int q = o >> 2;              // lane shift (floor)
            const int j = o & 3;               // register within set
            float w;
            if (q == 0) {
                w = Cv[j];
            } else if (q < 0) {
                // source lanes >= 64+q supply prev-group values
                float src = (lane >= 64 + q) ? Pv[j] : Cv[j];
                int addr = (q == -7) ? addr_m7 : (q == -6) ? addr_m6
                         : (q == -5) ? addr_m5 : (q == -4) ? addr_m4
                         : (q == -3) ? addr_m3 : (q == -2) ? addr_m2 : addr_m1;
                w = __int_as_float(__builtin_amdgcn_ds_bpermute(addr, __float_as_int(src)));
            } else {
                // source lanes < q supply next-group values
                float src = (lane < q) ? Nv[j] : Cv[j];
                int addr = (q == 1) ? addr_p1 : (q == 2) ? addr_p2
                         : (q == 3) ? addr_p3 : (q == 4) ? addr_p4
                         : (q == 5) ? addr_p5 : addr_p6;
                w = __int_as_float(__builtin_amdgcn_ds_bpermute(addr, __float_as_int(src)));
            }
#pragma unroll
            for (int k = 0; k < 4; ++k) {
                const int jj = k + 24 - o;
                if (jj >= 0 && jj < KLEN)
                    acc[k] = fmaf(kt[jj], w, acc[k]);
            }
        }

        // ---- candidates (exact reference arithmetic) ----
        const int tb = g * GRP + 4 * lane;
        int cand[4];
#pragma unroll
        for (int k = 0; k < 4; ++k) {
            float vfree = v_reset + acc[k] / 100.0f;   // true IEEE divide
            cand[k] = (vfree >= v_th) ? 1 : 0;
        }
        cand[0] &= (tb != 0);   // spikes[0] forced 0 (loop starts at t=1)

        const int cm = cand[0] | cand[1] | cand[2] | cand[3];
        const unsigned long long anyc = __ballot(cm != 0);

        float4 o0;
        if (anyc == 0ULL) {
            // No crossing in this 256-group: all spikes zero; any refractory
            // countdown (<=3) expires within the group.
            o0.x = o0.y = o0.z = o0.w = 0.0f;
            r0 = 0;
        } else {
            // ---- per-lane 4-step transfer map for incoming ref in {0..3} ----
            int s0 = 0, s1 = 1, s2 = 2, s3 = 3;
#pragma unroll
            for (int k = 0; k < 4; ++k) {
                const int c3 = cand[k] ? 3 : 0;
                s0 = (s0 > 0) ? (s0 - 1) : c3;
                s1 = (s1 > 0) ? (s1 - 1) : c3;
                s2 = (s2 > 0) ? (s2 - 1) : c3;
                s3 = (s3 > 0) ? (s3 - 1) : c3;
            }
            int P = s0 | (s1 << 2) | (s2 << 4) | (s3 << 6);

            // ---- inclusive prefix composition across 64 lanes ----
#pragma unroll
            for (int d = 1; d < 64; d <<= 1) {
                const int prev = __shfl_up(P, d, 64);
                const int comp = map_compose(prev, P);
                P = (lane >= d) ? comp : P;
            }
            const int Pprev = __shfl_up(P, 1, 64);
            const int sin0  = (lane == 0) ? r0 : ((Pprev >> (2 * r0)) & 3);
            const int Pfull = __shfl(P, 63, 64);
            r0 = (Pfull >> (2 * r0)) & 3;   // carry to next group

            // ---- replay with true incoming state ----
            int s = sin0;
            float sp[4];
#pragma unroll
            for (int k = 0; k < 4; ++k) {
                const int spike = (s == 0) & cand[k];
                sp[k] = spike ? 1.0f : 0.0f;
                s = (s > 0) ? (s - 1) : (cand[k] ? 3 : 0);
            }
            o0.x = sp[0]; o0.y = sp[1]; o0.z = sp[2]; o0.w = sp[3];
        }

        *(float4*)(Orow + tb) = o0;   // contiguous: lane i <-> byte 16i

        // ---- rotate register sets ----
#pragma unroll
        for (int j = 0; j < 4; ++j) { Pv[j] = Cv[j]; Cv[j] = Nv[j]; Nv[j] = Lv[j]; }
    }
}

extern "C" void kernel_launch(void* const* d_in, const int* in_sizes, int n_in,
                              void* d_out, int out_size, void* d_ws, size_t ws_size,
                              hipStream_t stream) {
    const float* I       = (const float*)d_in[0];
    const float* tau_m   = (const float*)d_in[1];
    const float* tau_s   = (const float*)d_in[2];
    const float* v_th    = (const float*)d_in[3];
    const float* v_reset = (const float*)d_in[4];
    float* out = (float*)d_out;

    srm_kernel<<<dim3(NROWS / WPB), dim3(256), 0, stream>>>(
        I, tau_m, tau_s, v_th, v_reset, out);
}